// Round 8
// baseline (184.795 us; speedup 1.0000x reference)
//
#include <hip/hip_runtime.h>
#include <hip/hip_bf16.h>

#define B_   8
#define DIM_ 512
#define T_   4096
#define H_   64
#define NC_  1024   // 2*B*H : cols 0..511 = eK*V (c=b*64+h), 512..1023 = eK

typedef __attribute__((ext_vector_type(8))) short short8;
typedef __attribute__((ext_vector_type(4))) float f32x4;

__device__ __forceinline__ unsigned short f2bf(float x) {
    __hip_bfloat16 h = __float2bfloat16(x);
    return *reinterpret_cast<unsigned short*>(&h);
}
__device__ __forceinline__ float bf2f(unsigned short u) {
    __hip_bfloat16 h = *reinterpret_cast<__hip_bfloat16*>(&u);
    return __bfloat162float(h);
}
__device__ __forceinline__ void gload16(const void* g, void* l) {
    __builtin_amdgcn_global_load_lds(
        (const __attribute__((address_space(1))) unsigned int*)g,
        (__attribute__((address_space(3))) unsigned int*)l, 16, 0, 0);
}

// ---------------------------------------------------------------------------
// K0: Aexp[t][s] = bf16(exp(wbias[t][s]))
// ---------------------------------------------------------------------------
__global__ __launch_bounds__(256) void ewb_kernel(
    const float* __restrict__ wb, unsigned short* __restrict__ Aexp)
{
    const int n4 = T_ * T_ / 4;
    int idx = blockIdx.x * blockDim.x + threadIdx.x;
    int stride = gridDim.x * blockDim.x;
    for (int i = idx; i < n4; i += stride) {
        float4 v = ((const float4*)wb)[i];
        ushort4 o;
        o.x = f2bf(__expf(v.x));
        o.y = f2bf(__expf(v.y));
        o.z = f2bf(__expf(v.z));
        o.w = f2bf(__expf(v.w));
        ((ushort4*)Aexp)[i] = o;
    }
}

// ---------------------------------------------------------------------------
// K0b: Wcat[192][512] bf16 from {wq,wk,wv}; bcat[192] f32 from {bq,bk,bv}.
// ---------------------------------------------------------------------------
__global__ __launch_bounds__(128) void wcat_kernel(
    const float* __restrict__ wq, const float* __restrict__ bq,
    const float* __restrict__ wk, const float* __restrict__ bk,
    const float* __restrict__ wv, const float* __restrict__ bv,
    unsigned short* __restrict__ Wcat, float* __restrict__ bcat)
{
    const int r = blockIdx.x;
    const int tid = threadIdx.x;
    const float* src = (r < 64) ? (wq + (size_t)r * DIM_)
                     : (r < 128) ? (wk + (size_t)(r - 64) * DIM_)
                                 : (wv + (size_t)(r - 128) * DIM_);
    const int d4 = tid * 4;
    float4 v = *(const float4*)&src[d4];
    ushort4 o;
    o.x = f2bf(v.x); o.y = f2bf(v.y); o.z = f2bf(v.z); o.w = f2bf(v.w);
    *(ushort4*)&Wcat[(size_t)r * DIM_ + d4] = o;
    if (tid == 0)
        bcat[r] = (r < 64) ? bq[r] : (r < 128) ? bk[r - 64] : bv[r - 128];
}

// ---------------------------------------------------------------------------
// K0c: wpb[512][64] bf16 from wp.
// ---------------------------------------------------------------------------
__global__ __launch_bounds__(256) void wpb_kernel(
    const float* __restrict__ wp, unsigned short* __restrict__ wpb)
{
    const int i = (blockIdx.x * 256 + threadIdx.x) * 4;
    float4 v = *(const float4*)&wp[i];
    ushort4 o;
    o.x = f2bf(v.x); o.y = f2bf(v.y); o.z = f2bf(v.z); o.w = f2bf(v.w);
    *(ushort4*)&wpb[i] = o;
}

// ---------------------------------------------------------------------------
// K1: fused transpose + QKV via MFMA.  grid (T/64, B), block 256 (4 waves).
// ---------------------------------------------------------------------------
__global__ __launch_bounds__(256) void xqkv_fused(
    const float* __restrict__ x, const unsigned short* __restrict__ Wcat,
    const float* __restrict__ bcat,
    unsigned short* __restrict__ Qb, unsigned short* __restrict__ SbT)
{
    __shared__ float xs[64 * 65];             // [d][t] f32, 16.6 KB
    __shared__ unsigned short Bs[192 * 64];   // [h][d] bf16, 24 KB

    const int tid = threadIdx.x;
    const int t0 = blockIdx.x * 64;
    const int b  = blockIdx.y;
    const int wid = tid >> 6, lane = tid & 63;

    f32x4 acc[12];
    const f32x4 vzero = {0.f, 0.f, 0.f, 0.f};
#pragma unroll
    for (int f = 0; f < 12; f++) acc[f] = vzero;

    const int rs  = tid >> 3;
    const int ks8 = (tid & 7) * 8;
    const unsigned short* Bg = Wcat + (size_t)rs * DIM_ + ks8;

    const int xrow = tid >> 4;
    const int xt4  = (tid & 15) * 4;

    const int t_in = lane & 15;
    const int g    = lane >> 4;

    for (int d0 = 0; d0 < DIM_; d0 += 64) {
#pragma unroll
        for (int p = 0; p < 4; p++) {
            const int d = p * 16 + xrow;
            float4 v = *(const float4*)&x[((size_t)b * DIM_ + d0 + d) * T_ + t0 + xt4];
            *(float4*)&xs[d * 65 + xt4] = v;
        }
#pragma unroll
        for (int it = 0; it < 6; it++)
            gload16(Bg + (size_t)(it * 32) * DIM_ + d0, (void*)&Bs[(it * 256 + tid) * 8]);
        __syncthreads();

        const int row_a = wid * 16 + t_in;
#pragma unroll
        for (int kk = 0; kk < 2; kk++) {
            union { unsigned short s[8]; short8 v; } af;
#pragma unroll
            for (int j = 0; j < 8; j++)
                af.s[j] = f2bf(xs[(kk * 32 + g * 8 + j) * 65 + row_a]);
            const int kr = kk * 32 + g * 8;
#pragma unroll
            for (int fn = 0; fn < 12; fn++) {
                short8 bf = *(const short8*)&Bs[(fn * 16 + t_in) * 64 + kr];
                acc[fn] = __builtin_amdgcn_mfma_f32_16x16x32_bf16(af.v, bf, acc[fn], 0, 0, 0);
            }
        }
        __syncthreads();
    }

    const int cc = t_in;
    const int t_base = t0 + wid * 16 + g * 4;

#pragma unroll
    for (int fn = 0; fn < 4; fn++) {
        const int h = fn * 16 + cc;
        const float bb = bcat[h];
#pragma unroll
        for (int r = 0; r < 4; r++)
            Qb[((size_t)b * T_ + t_base + r) * H_ + h] = f2bf(acc[fn][r] + bb);
    }
#pragma unroll
    for (int f = 0; f < 4; f++) {
        const int h = f * 16 + cc;
        const float bK = bcat[64 + h];
        const float bV = bcat[128 + h];
        ushort4 pk, pe;
        float e0 = __expf(acc[4 + f][0] + bK), v0 = acc[8 + f][0] + bV;
        float e1 = __expf(acc[4 + f][1] + bK), v1 = acc[8 + f][1] + bV;
        float e2 = __expf(acc[4 + f][2] + bK), v2 = acc[8 + f][2] + bV;
        float e3 = __expf(acc[4 + f][3] + bK), v3 = acc[8 + f][3] + bV;
        pe.x = f2bf(e0); pe.y = f2bf(e1); pe.z = f2bf(e2); pe.w = f2bf(e3);
        pk.x = f2bf(e0 * v0); pk.y = f2bf(e1 * v1); pk.z = f2bf(e2 * v2); pk.w = f2bf(e3 * v3);
        *(ushort4*)&SbT[(size_t)(b * 64 + h) * T_ + t_base] = pk;
        *(ushort4*)&SbT[(size_t)(512 + b * 64 + h) * T_ + t_base] = pe;
    }
}

// ---------------------------------------------------------------------------
// K2: 8-phase 256x256 GEMM, BK=64, split-K=SK (runtime 2 or 4).
// ND[ks][t][c] = sum_{s in K-range ks} Aexp[t][s] * SbT[c][s]
// 512 threads (8 waves, 2M x 4N).  LDS 128 KB: 2 bufs x (A 32K | B 32K),
// XOR-swizzled (col16 ^= row&7) for conflict-free ds_read_b128; staged via
// linear-dest global_load_lds with inverse-swizzled global source.
// Per K-tile kt (buf p=kt&1), 4 phases; phase q: ds_read A-frags fm=2q,2q+1
// (+all B at q0), stage 2 half-units, barrier, lgkm, setprio(1), 16 MFMA,
// setprio(0), barrier.  Stage plan (proven: issue >=1 barrier after dest's
// last read):  q0: A-Q2,Q3(kt+1)->buf 1-p;  q1: B-h0(kt+2)->buf p;
// q2: B-h1(kt+2);  q3: A-Q0,Q1(kt+2) then vmcnt(6)  [6 = q1..q3 stages of
// kt+2 in flight; everything older (all of kt+1) forced landed].
// ---------------------------------------------------------------------------
__global__ __launch_bounds__(512, 2) void aft_gemm_8ph(
    const unsigned short* __restrict__ Aexp,
    const unsigned short* __restrict__ SbT,
    unsigned short* __restrict__ ND, int SK)
{
    __shared__ unsigned short smem[65536];   // 128 KB

    const int tid  = threadIdx.x;
    const int wid  = tid >> 6, lane = tid & 63;
    const int wm   = wid >> 2, wn = wid & 3;
    const int la   = lane & 15, lg = lane >> 4;

    // XCD-aware bijective swizzle over nwg = 64*SK blocks (multiple of 8)
    const int nwg = 64 * SK;
    const int lin = blockIdx.x + blockIdx.y * 4 + blockIdx.z * 64;
    const int cpx = nwg >> 3;
    const int wg  = (lin & 7) * cpx + (lin >> 3);
    const int c0  = (wg & 3) * 256;
    const int t0  = ((wg >> 2) & 15) * 256;
    const int ks  = wg >> 6;
    const int Kblk  = T_ / SK;
    const int sbase = ks * Kblk;
    const int NT    = Kblk >> 6;

    f32x4 acc[8][4];
    const f32x4 vzero = {0.f, 0.f, 0.f, 0.f};
#pragma unroll
    for (int i = 0; i < 8; i++)
#pragma unroll
        for (int j = 0; j < 4; j++) acc[i][j] = vzero;

    const int lr8 = tid >> 3, c16 = tid & 7;

    // stage A-quarter q (rows {32q..+31} u {128+32q..+31}) of K-tile T -> buf p
    auto stA = [&](int q, int T, int p) {
        const int tr = (lr8 < 32) ? (32 * q + lr8) : (96 + 32 * q + lr8);
        const unsigned short* src = Aexp + (size_t)(t0 + tr) * T_
                                  + sbase + T * 64 + ((c16 ^ (tr & 7)) * 8);
        gload16(src, (void*)&smem[p * 32768 + tr * 64 + c16 * 8]);
    };
    // stage B rows [128h+64j .. +63] of K-tile T -> buf p
    auto stB = [&](int h, int j, int T, int p) {
        const int tr = 128 * h + 64 * j + lr8;
        const unsigned short* src = SbT + (size_t)(c0 + tr) * T_
                                  + sbase + T * 64 + ((c16 ^ (tr & 7)) * 8);
        gload16(src, (void*)&smem[p * 32768 + 16384 + tr * 64 + c16 * 8]);
    };

    // prologue: K-tile 0 fully (8 loads), K-tile 1 B+A-Q0,Q1 (6 loads)
    stB(0, 0, 0, 0); stB(0, 1, 0, 0); stB(1, 0, 0, 0); stB(1, 1, 0, 0);
    stA(0, 0, 0);    stA(1, 0, 0);    stA(2, 0, 0);    stA(3, 0, 0);
    stB(0, 0, 1, 1); stB(0, 1, 1, 1); stB(1, 0, 1, 1); stB(1, 1, 1, 1);
    stA(0, 1, 1);    stA(1, 1, 1);
    asm volatile("s_waitcnt vmcnt(6)" ::: "memory");   // K0 landed
    __builtin_amdgcn_s_barrier();

    for (int kt = 0; kt < NT; ++kt) {
        const int p = kt & 1;
        const unsigned short* Ab = smem + p * 32768;
        const unsigned short* Bb = Ab + 16384;
        short8 bfr[4][2];

        // ---- phase 0: read B(all) + A fm=0,1; stage A-Q2,Q3(kt+1) ----
        {
            short8 af[2][2];
#pragma unroll
            for (int i = 0; i < 2; ++i) {
                const int row = 128 * wm + 16 * i + la;
#pragma unroll
                for (int kk = 0; kk < 2; ++kk)
                    af[i][kk] = *(const short8*)&Ab[row * 64 + (((kk * 4 + lg) ^ (row & 7)) * 8)];
            }
#pragma unroll
            for (int fn = 0; fn < 4; ++fn) {
                const int row = 64 * wn + 16 * fn + la;
#pragma unroll
                for (int kk = 0; kk < 2; ++kk)
                    bfr[fn][kk] = *(const short8*)&Bb[row * 64 + (((kk * 4 + lg) ^ (row & 7)) * 8)];
            }
            if (kt + 1 < NT) { stA(2, kt + 1, 1 - p); stA(3, kt + 1, 1 - p); }
            __builtin_amdgcn_s_barrier();
            asm volatile("s_waitcnt lgkmcnt(0)" ::: "memory");
            __builtin_amdgcn_sched_barrier(0);
            __builtin_amdgcn_s_setprio(1);
#pragma unroll
            for (int i = 0; i < 2; ++i)
#pragma unroll
                for (int fn = 0; fn < 4; ++fn)
#pragma unroll
                    for (int kk = 0; kk < 2; ++kk)
                        acc[i][fn] = __builtin_amdgcn_mfma_f32_16x16x32_bf16(
                            af[i][kk], bfr[fn][kk], acc[i][fn], 0, 0, 0);
            __builtin_amdgcn_s_setprio(0);
            __builtin_amdgcn_s_barrier();
        }
        // ---- phases 1..3 ----
#pragma unroll
        for (int q = 1; q < 4; ++q) {
            short8 af[2][2];
#pragma unroll
            for (int i = 0; i < 2; ++i) {
                const int row = 128 * wm + 16 * (2 * q + i) + la;
#pragma unroll
                for (int kk = 0; kk < 2; ++kk)
                    af[i][kk] = *(const short8*)&Ab[row * 64 + (((kk * 4 + lg) ^ (row & 7)) * 8)];
            }
            if (kt + 2 < NT) {
                if (q == 1)      { stB(0, 0, kt + 2, p); stB(0, 1, kt + 2, p); }
                else if (q == 2) { stB(1, 0, kt + 2, p); stB(1, 1, kt + 2, p); }
                else             { stA(0, kt + 2, p);    stA(1, kt + 2, p);    }
            }
            if (q == 3) asm volatile("s_waitcnt vmcnt(6)" ::: "memory");
            __builtin_amdgcn_s_barrier();
            asm volatile("s_waitcnt lgkmcnt(0)" ::: "memory");
            __builtin_amdgcn_sched_barrier(0);
            __builtin_amdgcn_s_setprio(1);
#pragma unroll
            for (int i = 0; i < 2; ++i)
#pragma unroll
                for (int fn = 0; fn < 4; ++fn)
#pragma unroll
                    for (int kk = 0; kk < 2; ++kk)
                        acc[2 * q + i][fn] = __builtin_amdgcn_mfma_f32_16x16x32_bf16(
                            af[i][kk], bfr[fn][kk], acc[2 * q + i][fn], 0, 0, 0);
            __builtin_amdgcn_s_setprio(0);
            __builtin_amdgcn_s_barrier();
        }
    }

    // C-write: bf16 partials
    unsigned short* NDp = ND + (size_t)ks * T_ * NC_;
    const int r4 = lg * 4;
#pragma unroll
    for (int fm = 0; fm < 8; ++fm)
#pragma unroll
        for (int fn = 0; fn < 4; ++fn)
#pragma unroll
            for (int r = 0; r < 4; ++r) {
                const int t = t0 + 128 * wm + 16 * fm + r4 + r;
                const int c = c0 + 64 * wn + 16 * fn + la;
                NDp[(size_t)t * NC_ + c] = f2bf(acc[fm][fn][r]);
            }
}

// ---------------------------------------------------------------------------
// K3: epilogue via MFMA.  grid (T/64, B), block 256 (4 waves).
// y = sigmoid(Q)*num/den (bf16, XOR-swizzled LDS); out = y @ wpb.T + bp.
// ---------------------------------------------------------------------------
__global__ __launch_bounds__(256) void epilogue_mfma(
    const unsigned short* __restrict__ Qb, const unsigned short* __restrict__ ND,
    const unsigned short* __restrict__ wpb, const float* __restrict__ bp,
    float* __restrict__ out, int write_both, int SK)
{
    __shared__ unsigned short smem[36864];      // 72 KB
    unsigned short* y_s  = smem;                // 8 KB, swizzled [t][h]
    unsigned short* wp_s = smem + 4096;         // 64 KB, swizzled [d][h]
    float* st = (float*)smem;                   // bounce [64][260] f32

    const int tid  = threadIdx.x;
    const int t0   = blockIdx.x * 64;
    const int b    = blockIdx.y;
    const int wid  = tid >> 6, lane = tid & 63;
    const size_t SZ_COPY = (size_t)B_ * T_ * DIM_;

    {
        const int rs = tid >> 3;
        const int c8 = tid & 7;
#pragma unroll
        for (int p = 0; p < 16; p++) {
            const int row = p * 32 + rs;
            gload16(wpb + (size_t)row * 64 + ((c8 ^ (row & 7)) << 3),
                    (void*)&wp_s[((size_t)row * 8 + c8) * 8]);
        }
    }
    {
        const int t   = tid >> 2;
        const int h16 = (tid & 3) * 16;
        const size_t qoff = ((size_t)b * T_ + t0 + t) * H_ + h16;
        const size_t noff = (size_t)(t0 + t) * NC_ + b * 64 + h16;
        float yv[16];
#pragma unroll
        for (int u = 0; u < 16; u++) {
            float num = 0.f, den = 0.f;
            for (int pp = 0; pp < SK; ++pp) {
                const unsigned short* NDp = ND + (size_t)pp * T_ * NC_;
                num += bf2f(NDp[noff + u]);
                den += bf2f(NDp[noff + 512 + u]);
            }
            float q = bf2f(Qb[qoff + u]);
            yv[u] = (1.f / (1.f + __expf(-q))) * num / den;
        }
#pragma unroll
        for (int u = 0; u < 2; u++) {
            const int h8 = (tid & 3) * 2 + u;
            union { unsigned short s[8]; short8 v; } pk;
#pragma unroll
            for (int e = 0; e < 8; e++) pk.s[e] = f2bf(yv[u * 8 + e]);
            *(short8*)((char*)y_s + t * 128 + ((h8 ^ (t & 7)) << 4)) = pk.v;
        }
    }
    __syncthreads();

    f32x4 acc[32];
    const f32x4 vzero = {0.f, 0.f, 0.f, 0.f};
#pragma unroll
    for (int f = 0; f < 32; f++) acc[f] = vzero;

    const int ra = wid * 16 + (lane & 15);
    short8 af[2];
#pragma unroll
    for (int kk = 0; kk < 2; kk++)
        af[kk] = *(const short8*)((char*)y_s + ra * 128 +
                                  (((kk * 4 + (lane >> 4)) ^ (ra & 7)) << 4));
#pragma unroll
    for (int fn = 0; fn < 32; fn++) {
        const int rb = fn * 16 + (lane & 15);
#pragma unroll
        for (int kk = 0; kk < 2; kk++) {
            short8 bf = *(const short8*)((char*)wp_s + rb * 128 +
                                         (((kk * 4 + (lane >> 4)) ^ (rb & 7)) << 4));
            acc[fn] = __builtin_amdgcn_mfma_f32_16x16x32_bf16(af[kk], bf, acc[fn], 0, 0, 0);
        }
    }
    __syncthreads();

    const int g  = lane >> 4;
    const int cc = lane & 15;
    float4 bb01[2];
    bb01[0] = *(const float4*)&bp[lane * 4];
    bb01[1] = *(const float4*)&bp[256 + lane * 4];

#pragma unroll
    for (int ch = 0; ch < 2; ch++) {
        if (ch) __syncthreads();
#pragma unroll
        for (int f = 0; f < 16; f++)
#pragma unroll
            for (int r = 0; r < 4; r++)
                st[(wid * 16 + g * 4 + r) * 260 + f * 16 + cc] = acc[ch * 16 + f][r];
        __syncthreads();
        const float4 bb = bb01[ch];
#pragma unroll
        for (int it = 0; it < 16; it++) {
            const int row = it * 4 + wid;
            float4 v = *(const float4*)&st[row * 260 + lane * 4];
            float4 o = {v.x + bb.x, v.y + bb.y, v.z + bb.z, v.w + bb.w};
            const size_t obase = ((size_t)b * T_ + t0 + row) * DIM_ + ch * 256 + lane * 4;
            *(float4*)&out[obase] = o;
            if (write_both)
                *(float4*)&out[SZ_COPY + obase] = o;
        }
    }
}

__global__ void dup_kernel(const float4* __restrict__ src, float4* __restrict__ dst, int n4)
{
    int idx = blockIdx.x * blockDim.x + threadIdx.x;
    int stride = gridDim.x * blockDim.x;
    for (int k = idx; k < n4; k += stride) dst[k] = src[k];
}

extern "C" void kernel_launch(void* const* d_in, const int* in_sizes, int n_in,
                              void* d_out, int out_size, void* d_ws, size_t ws_size,
                              hipStream_t stream)
{
    const float* x     = (const float*)d_in[0];
    const float* wq    = (const float*)d_in[1];
    const float* bq    = (const float*)d_in[2];
    const float* wk    = (const float*)d_in[3];
    const float* bk    = (const float*)d_in[4];
    const float* wv    = (const float*)d_in[5];
    const float* bv    = (const float*)d_in[6];
    const float* wp    = (const float*)d_in[7];
    const float* bp    = (const float*)d_in[8];
    const float* wbias = (const float*)d_in[9];
    float* out = (float*)d_out;

    const size_t SZ_COPY = (size_t)B_ * T_ * DIM_;

    // layout(SK): Aexp 33.5M @0; ND SK*8.4M @33.5M; SbT 8.4M; Qb 4.2M;
    //             Wcat 192K; wpb 64K; bcat 1K
    auto need = [](int SK) -> size_t {
        return 33554432u + (size_t)SK * 8388608u + 8388608u + 4194304u
             + 196608u + 65536u + 1024u;
    };
    int SK, write_both;
    char* R;
    if (ws_size >= need(4)) {
        SK = 4; write_both = 1; R = (char*)d_ws;
    } else {
        SK = 2; write_both = 0; R = (char*)(out + SZ_COPY);  // 63.2MB <= 67MB
    }
    size_t off = 0;
    unsigned short* Aexp  = (unsigned short*)(R + off); off += 33554432u;
    unsigned short* NDbuf = (unsigned short*)(R + off); off += (size_t)SK * 8388608u;
    unsigned short* SbT   = (unsigned short*)(R + off); off += 8388608u;
    unsigned short* Qbuf  = (unsigned short*)(R + off); off += 4194304u;
    unsigned short* Wcat  = (unsigned short*)(R + off); off += 196608u;
    unsigned short* wpb   = (unsigned short*)(R + off); off += 65536u;
    float*          bcat  = (float*)(R + off);

    ewb_kernel<<<2048, 256, 0, stream>>>(wbias, Aexp);
    wcat_kernel<<<192, 128, 0, stream>>>(wq, bq, wk, bk, wv, bv, Wcat, bcat);
    wpb_kernel<<<32, 256, 0, stream>>>(wp, wpb);
    xqkv_fused<<<dim3(T_ / 64, B_), 256, 0, stream>>>(x, Wcat, bcat, Qbuf, SbT);
    aft_gemm_8ph<<<dim3(4, 16, SK), 512, 0, stream>>>(Aexp, SbT, NDbuf, SK);
    epilogue_mfma<<<dim3(T_ / 64, B_), 256, 0, stream>>>(Qbuf, NDbuf, wpb, bp, out,
                                                         write_both, SK);
    if (!write_both)
        dup_kernel<<<2048, 256, 0, stream>>>((const float4*)out,
                                             (float4*)(out + SZ_COPY),
                                             (int)(SZ_COPY / 4));
}

// Round 9
// 137.467 us; speedup vs baseline: 1.3443x; 1.3443x over previous
//
#include <hip/hip_runtime.h>
#include <hip/hip_bf16.h>

#define B_   8
#define DIM_ 512
#define T_   4096
#define H_   64
#define NC_  1024   // 2*B*H : cols 0..511 = eK*V (c=b*64+h), 512..1023 = eK

typedef __attribute__((ext_vector_type(8))) short short8;
typedef __attribute__((ext_vector_type(4))) float f32x4;

__device__ __forceinline__ unsigned short f2bf(float x) {
    __hip_bfloat16 h = __float2bfloat16(x);
    return *reinterpret_cast<unsigned short*>(&h);
}
__device__ __forceinline__ float bf2f(unsigned short u) {
    __hip_bfloat16 h = *reinterpret_cast<__hip_bfloat16*>(&u);
    return __bfloat162float(h);
}
__device__ __forceinline__ void gload16(const void* g, void* l) {
    __builtin_amdgcn_global_load_lds(
        (const __attribute__((address_space(1))) unsigned int*)g,
        (__attribute__((address_space(3))) unsigned int*)l, 16, 0, 0);
}

// ---------------------------------------------------------------------------
// K0: Aexp[t][s] = bf16(exp(wbias[t][s]))
// ---------------------------------------------------------------------------
__global__ __launch_bounds__(256) void ewb_kernel(
    const float* __restrict__ wb, unsigned short* __restrict__ Aexp)
{
    const int n4 = T_ * T_ / 4;
    int idx = blockIdx.x * blockDim.x + threadIdx.x;
    int stride = gridDim.x * blockDim.x;
    for (int i = idx; i < n4; i += stride) {
        float4 v = ((const float4*)wb)[i];
        ushort4 o;
        o.x = f2bf(__expf(v.x));
        o.y = f2bf(__expf(v.y));
        o.z = f2bf(__expf(v.z));
        o.w = f2bf(__expf(v.w));
        ((ushort4*)Aexp)[i] = o;
    }
}

// ---------------------------------------------------------------------------
// K0b: Wcat[192][512] bf16 from {wq,wk,wv}; bcat[192] f32 from {bq,bk,bv}.
// ---------------------------------------------------------------------------
__global__ __launch_bounds__(128) void wcat_kernel(
    const float* __restrict__ wq, const float* __restrict__ bq,
    const float* __restrict__ wk, const float* __restrict__ bk,
    const float* __restrict__ wv, const float* __restrict__ bv,
    unsigned short* __restrict__ Wcat, float* __restrict__ bcat)
{
    const int r = blockIdx.x;
    const int tid = threadIdx.x;
    const float* src = (r < 64) ? (wq + (size_t)r * DIM_)
                     : (r < 128) ? (wk + (size_t)(r - 64) * DIM_)
                                 : (wv + (size_t)(r - 128) * DIM_);
    const int d4 = tid * 4;
    float4 v = *(const float4*)&src[d4];
    ushort4 o;
    o.x = f2bf(v.x); o.y = f2bf(v.y); o.z = f2bf(v.z); o.w = f2bf(v.w);
    *(ushort4*)&Wcat[(size_t)r * DIM_ + d4] = o;
    if (tid == 0)
        bcat[r] = (r < 64) ? bq[r] : (r < 128) ? bk[r - 64] : bv[r - 128];
}

// ---------------------------------------------------------------------------
// K0c: wpb[512][64] bf16 from wp.
// ---------------------------------------------------------------------------
__global__ __launch_bounds__(256) void wpb_kernel(
    const float* __restrict__ wp, unsigned short* __restrict__ wpb)
{
    const int i = (blockIdx.x * 256 + threadIdx.x) * 4;
    float4 v = *(const float4*)&wp[i];
    ushort4 o;
    o.x = f2bf(v.x); o.y = f2bf(v.y); o.z = f2bf(v.z); o.w = f2bf(v.w);
    *(ushort4*)&wpb[i] = o;
}

// ---------------------------------------------------------------------------
// K1: fused transpose + QKV via MFMA.  grid (T/64, B), block 256 (4 waves).
// ---------------------------------------------------------------------------
__global__ __launch_bounds__(256) void xqkv_fused(
    const float* __restrict__ x, const unsigned short* __restrict__ Wcat,
    const float* __restrict__ bcat,
    unsigned short* __restrict__ Qb, unsigned short* __restrict__ SbT)
{
    __shared__ float xs[64 * 65];             // [d][t] f32, 16.6 KB
    __shared__ unsigned short Bs[192 * 64];   // [h][d] bf16, 24 KB

    const int tid = threadIdx.x;
    const int t0 = blockIdx.x * 64;
    const int b  = blockIdx.y;
    const int wid = tid >> 6, lane = tid & 63;

    f32x4 acc[12];
    const f32x4 vzero = {0.f, 0.f, 0.f, 0.f};
#pragma unroll
    for (int f = 0; f < 12; f++) acc[f] = vzero;

    const int rs  = tid >> 3;
    const int ks8 = (tid & 7) * 8;
    const unsigned short* Bg = Wcat + (size_t)rs * DIM_ + ks8;

    const int xrow = tid >> 4;
    const int xt4  = (tid & 15) * 4;

    const int t_in = lane & 15;
    const int g    = lane >> 4;

    for (int d0 = 0; d0 < DIM_; d0 += 64) {
#pragma unroll
        for (int p = 0; p < 4; p++) {
            const int d = p * 16 + xrow;
            float4 v = *(const float4*)&x[((size_t)b * DIM_ + d0 + d) * T_ + t0 + xt4];
            *(float4*)&xs[d * 65 + xt4] = v;
        }
#pragma unroll
        for (int it = 0; it < 6; it++)
            gload16(Bg + (size_t)(it * 32) * DIM_ + d0, (void*)&Bs[(it * 256 + tid) * 8]);
        __syncthreads();

        const int row_a = wid * 16 + t_in;
#pragma unroll
        for (int kk = 0; kk < 2; kk++) {
            union { unsigned short s[8]; short8 v; } af;
#pragma unroll
            for (int j = 0; j < 8; j++)
                af.s[j] = f2bf(xs[(kk * 32 + g * 8 + j) * 65 + row_a]);
            const int kr = kk * 32 + g * 8;
#pragma unroll
            for (int fn = 0; fn < 12; fn++) {
                short8 bf = *(const short8*)&Bs[(fn * 16 + t_in) * 64 + kr];
                acc[fn] = __builtin_amdgcn_mfma_f32_16x16x32_bf16(af.v, bf, acc[fn], 0, 0, 0);
            }
        }
        __syncthreads();
    }

    const int cc = t_in;
    const int t_base = t0 + wid * 16 + g * 4;

#pragma unroll
    for (int fn = 0; fn < 4; fn++) {
        const int h = fn * 16 + cc;
        const float bb = bcat[h];
#pragma unroll
        for (int r = 0; r < 4; r++)
            Qb[((size_t)b * T_ + t_base + r) * H_ + h] = f2bf(acc[fn][r] + bb);
    }
#pragma unroll
    for (int f = 0; f < 4; f++) {
        const int h = f * 16 + cc;
        const float bK = bcat[64 + h];
        const float bV = bcat[128 + h];
        ushort4 pk, pe;
        float e0 = __expf(acc[4 + f][0] + bK), v0 = acc[8 + f][0] + bV;
        float e1 = __expf(acc[4 + f][1] + bK), v1 = acc[8 + f][1] + bV;
        float e2 = __expf(acc[4 + f][2] + bK), v2 = acc[8 + f][2] + bV;
        float e3 = __expf(acc[4 + f][3] + bK), v3 = acc[8 + f][3] + bV;
        pe.x = f2bf(e0); pe.y = f2bf(e1); pe.z = f2bf(e2); pe.w = f2bf(e3);
        pk.x = f2bf(e0 * v0); pk.y = f2bf(e1 * v1); pk.z = f2bf(e2 * v2); pk.w = f2bf(e3 * v3);
        *(ushort4*)&SbT[(size_t)(b * 64 + h) * T_ + t_base] = pk;
        *(ushort4*)&SbT[(size_t)(512 + b * 64 + h) * T_ + t_base] = pe;
    }
}

// ---------------------------------------------------------------------------
// K2: 8-phase 256x256 GEMM, BK=64, split-K=SK (runtime 2 or 4).
// (unchanged from round 8 — absmax-clean, schedule per T2+T3+T4+T5)
// ---------------------------------------------------------------------------
__global__ __launch_bounds__(512, 2) void aft_gemm_8ph(
    const unsigned short* __restrict__ Aexp,
    const unsigned short* __restrict__ SbT,
    unsigned short* __restrict__ ND, int SK)
{
    __shared__ unsigned short smem[65536];   // 128 KB

    const int tid  = threadIdx.x;
    const int wid  = tid >> 6, lane = tid & 63;
    const int wm   = wid >> 2, wn = wid & 3;
    const int la   = lane & 15, lg = lane >> 4;

    const int nwg = 64 * SK;
    const int lin = blockIdx.x + blockIdx.y * 4 + blockIdx.z * 64;
    const int cpx = nwg >> 3;
    const int wg  = (lin & 7) * cpx + (lin >> 3);
    const int c0  = (wg & 3) * 256;
    const int t0  = ((wg >> 2) & 15) * 256;
    const int ks  = wg >> 6;
    const int Kblk  = T_ / SK;
    const int sbase = ks * Kblk;
    const int NT    = Kblk >> 6;

    f32x4 acc[8][4];
    const f32x4 vzero = {0.f, 0.f, 0.f, 0.f};
#pragma unroll
    for (int i = 0; i < 8; i++)
#pragma unroll
        for (int j = 0; j < 4; j++) acc[i][j] = vzero;

    const int lr8 = tid >> 3, c16 = tid & 7;

    auto stA = [&](int q, int T, int p) {
        const int tr = (lr8 < 32) ? (32 * q + lr8) : (96 + 32 * q + lr8);
        const unsigned short* src = Aexp + (size_t)(t0 + tr) * T_
                                  + sbase + T * 64 + ((c16 ^ (tr & 7)) * 8);
        gload16(src, (void*)&smem[p * 32768 + tr * 64 + c16 * 8]);
    };
    auto stB = [&](int h, int j, int T, int p) {
        const int tr = 128 * h + 64 * j + lr8;
        const unsigned short* src = SbT + (size_t)(c0 + tr) * T_
                                  + sbase + T * 64 + ((c16 ^ (tr & 7)) * 8);
        gload16(src, (void*)&smem[p * 32768 + 16384 + tr * 64 + c16 * 8]);
    };

    stB(0, 0, 0, 0); stB(0, 1, 0, 0); stB(1, 0, 0, 0); stB(1, 1, 0, 0);
    stA(0, 0, 0);    stA(1, 0, 0);    stA(2, 0, 0);    stA(3, 0, 0);
    stB(0, 0, 1, 1); stB(0, 1, 1, 1); stB(1, 0, 1, 1); stB(1, 1, 1, 1);
    stA(0, 1, 1);    stA(1, 1, 1);
    asm volatile("s_waitcnt vmcnt(6)" ::: "memory");
    __builtin_amdgcn_s_barrier();

    for (int kt = 0; kt < NT; ++kt) {
        const int p = kt & 1;
        const unsigned short* Ab = smem + p * 32768;
        const unsigned short* Bb = Ab + 16384;
        short8 bfr[4][2];

        {
            short8 af[2][2];
#pragma unroll
            for (int i = 0; i < 2; ++i) {
                const int row = 128 * wm + 16 * i + la;
#pragma unroll
                for (int kk = 0; kk < 2; ++kk)
                    af[i][kk] = *(const short8*)&Ab[row * 64 + (((kk * 4 + lg) ^ (row & 7)) * 8)];
            }
#pragma unroll
            for (int fn = 0; fn < 4; ++fn) {
                const int row = 64 * wn + 16 * fn + la;
#pragma unroll
                for (int kk = 0; kk < 2; ++kk)
                    bfr[fn][kk] = *(const short8*)&Bb[row * 64 + (((kk * 4 + lg) ^ (row & 7)) * 8)];
            }
            if (kt + 1 < NT) { stA(2, kt + 1, 1 - p); stA(3, kt + 1, 1 - p); }
            __builtin_amdgcn_s_barrier();
            asm volatile("s_waitcnt lgkmcnt(0)" ::: "memory");
            __builtin_amdgcn_sched_barrier(0);
            __builtin_amdgcn_s_setprio(1);
#pragma unroll
            for (int i = 0; i < 2; ++i)
#pragma unroll
                for (int fn = 0; fn < 4; ++fn)
#pragma unroll
                    for (int kk = 0; kk < 2; ++kk)
                        acc[i][fn] = __builtin_amdgcn_mfma_f32_16x16x32_bf16(
                            af[i][kk], bfr[fn][kk], acc[i][fn], 0, 0, 0);
            __builtin_amdgcn_s_setprio(0);
            __builtin_amdgcn_s_barrier();
        }
#pragma unroll
        for (int q = 1; q < 4; ++q) {
            short8 af[2][2];
#pragma unroll
            for (int i = 0; i < 2; ++i) {
                const int row = 128 * wm + 16 * (2 * q + i) + la;
#pragma unroll
                for (int kk = 0; kk < 2; ++kk)
                    af[i][kk] = *(const short8*)&Ab[row * 64 + (((kk * 4 + lg) ^ (row & 7)) * 8)];
            }
            if (kt + 2 < NT) {
                if (q == 1)      { stB(0, 0, kt + 2, p); stB(0, 1, kt + 2, p); }
                else if (q == 2) { stB(1, 0, kt + 2, p); stB(1, 1, kt + 2, p); }
                else             { stA(0, kt + 2, p);    stA(1, kt + 2, p);    }
            }
            if (q == 3) asm volatile("s_waitcnt vmcnt(6)" ::: "memory");
            __builtin_amdgcn_s_barrier();
            asm volatile("s_waitcnt lgkmcnt(0)" ::: "memory");
            __builtin_amdgcn_sched_barrier(0);
            __builtin_amdgcn_s_setprio(1);
#pragma unroll
            for (int i = 0; i < 2; ++i)
#pragma unroll
                for (int fn = 0; fn < 4; ++fn)
#pragma unroll
                    for (int kk = 0; kk < 2; ++kk)
                        acc[2 * q + i][fn] = __builtin_amdgcn_mfma_f32_16x16x32_bf16(
                            af[i][kk], bfr[fn][kk], acc[2 * q + i][fn], 0, 0, 0);
            __builtin_amdgcn_s_setprio(0);
            __builtin_amdgcn_s_barrier();
        }
    }

    unsigned short* NDp = ND + (size_t)ks * T_ * NC_;
    const int r4 = lg * 4;
#pragma unroll
    for (int fm = 0; fm < 8; ++fm)
#pragma unroll
        for (int fn = 0; fn < 4; ++fn)
#pragma unroll
            for (int r = 0; r < 4; ++r) {
                const int t = t0 + 128 * wm + 16 * fm + r4 + r;
                const int c = c0 + 64 * wn + 16 * fn + la;
                NDp[(size_t)t * NC_ + c] = f2bf(acc[fm][fn][r]);
            }
}

// ---------------------------------------------------------------------------
// K3: epilogue via MFMA.  grid (T/64, B), block 256 (4 waves).
// SK is a COMPILE-TIME template param: ND partial reduction is pp-outer
// unrolled with short8 (16B) vector loads — no runtime loop between
// adjacent loads (round-8 lesson: that scalarized to 128x 2B loads,
// L1-thrash, 5x HBM over-fetch).
// ---------------------------------------------------------------------------
template <int SK>
__global__ __launch_bounds__(256) void epilogue_mfma(
    const unsigned short* __restrict__ Qb, const unsigned short* __restrict__ ND,
    const unsigned short* __restrict__ wpb, const float* __restrict__ bp,
    float* __restrict__ out, int write_both)
{
    __shared__ unsigned short smem[36864];      // 72 KB
    unsigned short* y_s  = smem;                // 8 KB, swizzled [t][h]
    unsigned short* wp_s = smem + 4096;         // 64 KB, swizzled [d][h]
    float* st = (float*)smem;                   // bounce [64][260] f32

    const int tid  = threadIdx.x;
    const int t0   = blockIdx.x * 64;
    const int b    = blockIdx.y;
    const int wid  = tid >> 6, lane = tid & 63;
    const size_t SZ_COPY = (size_t)B_ * T_ * DIM_;

    {
        const int rs = tid >> 3;
        const int c8 = tid & 7;
#pragma unroll
        for (int p = 0; p < 16; p++) {
            const int row = p * 32 + rs;
            gload16(wpb + (size_t)row * 64 + ((c8 ^ (row & 7)) << 3),
                    (void*)&wp_s[((size_t)row * 8 + c8) * 8]);
        }
    }
    {
        const int t   = tid >> 2;
        const int h16 = (tid & 3) * 16;
        const size_t qoff = ((size_t)b * T_ + t0 + t) * H_ + h16;
        const size_t noff = (size_t)(t0 + t) * NC_ + b * 64 + h16;

        float num[16], den[16];
#pragma unroll
        for (int e = 0; e < 16; e++) { num[e] = 0.f; den[e] = 0.f; }
#pragma unroll
        for (int pp = 0; pp < SK; ++pp) {
            const unsigned short* P = ND + (size_t)pp * T_ * NC_ + noff;
            short8 n0 = *(const short8*)&P[0];
            short8 n1 = *(const short8*)&P[8];
            short8 d0 = *(const short8*)&P[512];
            short8 d1 = *(const short8*)&P[520];
#pragma unroll
            for (int e = 0; e < 8; e++) {
                num[e]     += bf2f((unsigned short)n0[e]);
                num[8 + e] += bf2f((unsigned short)n1[e]);
                den[e]     += bf2f((unsigned short)d0[e]);
                den[8 + e] += bf2f((unsigned short)d1[e]);
            }
        }
        short8 q0 = *(const short8*)&Qb[qoff];
        short8 q1 = *(const short8*)&Qb[qoff + 8];
        float yv[16];
#pragma unroll
        for (int e = 0; e < 8; e++) {
            float qa = bf2f((unsigned short)q0[e]);
            float qb = bf2f((unsigned short)q1[e]);
            yv[e]     = (1.f / (1.f + __expf(-qa))) * num[e] / den[e];
            yv[8 + e] = (1.f / (1.f + __expf(-qb))) * num[8 + e] / den[8 + e];
        }
#pragma unroll
        for (int u = 0; u < 2; u++) {
            const int h8 = (tid & 3) * 2 + u;
            union { unsigned short s[8]; short8 v; } pk;
#pragma unroll
            for (int e = 0; e < 8; e++) pk.s[e] = f2bf(yv[u * 8 + e]);
            *(short8*)((char*)y_s + t * 128 + ((h8 ^ (t & 7)) << 4)) = pk.v;
        }
    }
    __syncthreads();

    f32x4 acc[32];
    const f32x4 vzero = {0.f, 0.f, 0.f, 0.f};
#pragma unroll
    for (int f = 0; f < 32; f++) acc[f] = vzero;

    const int ra = wid * 16 + (lane & 15);
    short8 af[2];
#pragma unroll
    for (int kk = 0; kk < 2; kk++)
        af[kk] = *(const short8*)((char*)y_s + ra * 128 +
                                  (((kk * 4 + (lane >> 4)) ^ (ra & 7)) << 4));
#pragma unroll
    for (int fn = 0; fn < 32; fn++) {
        const int rb = fn * 16 + (lane & 15);
#pragma unroll
        for (int kk = 0; kk < 2; kk++) {
            short8 bf = *(const short8*)((char*)wp_s + rb * 128 +
                                         (((kk * 4 + (lane >> 4)) ^ (rb & 7)) << 4));
            acc[fn] = __builtin_amdgcn_mfma_f32_16x16x32_bf16(af[kk], bf, acc[fn], 0, 0, 0);
        }
    }
    __syncthreads();

    const int g  = lane >> 4;
    const int cc = lane & 15;
    float4 bb01[2];
    bb01[0] = *(const float4*)&bp[lane * 4];
    bb01[1] = *(const float4*)&bp[256 + lane * 4];

#pragma unroll
    for (int ch = 0; ch < 2; ch++) {
        if (ch) __syncthreads();
#pragma unroll
        for (int f = 0; f < 16; f++)
#pragma unroll
            for (int r = 0; r < 4; r++)
                st[(wid * 16 + g * 4 + r) * 260 + f * 16 + cc] = acc[ch * 16 + f][r];
        __syncthreads();
        const float4 bb = bb01[ch];
#pragma unroll
        for (int it = 0; it < 16; it++) {
            const int row = it * 4 + wid;
            float4 v = *(const float4*)&st[row * 260 + lane * 4];
            float4 o = {v.x + bb.x, v.y + bb.y, v.z + bb.z, v.w + bb.w};
            const size_t obase = ((size_t)b * T_ + t0 + row) * DIM_ + ch * 256 + lane * 4;
            *(float4*)&out[obase] = o;
            if (write_both)
                *(float4*)&out[SZ_COPY + obase] = o;
        }
    }
}

__global__ void dup_kernel(const float4* __restrict__ src, float4* __restrict__ dst, int n4)
{
    int idx = blockIdx.x * blockDim.x + threadIdx.x;
    int stride = gridDim.x * blockDim.x;
    for (int k = idx; k < n4; k += stride) dst[k] = src[k];
}

extern "C" void kernel_launch(void* const* d_in, const int* in_sizes, int n_in,
                              void* d_out, int out_size, void* d_ws, size_t ws_size,
                              hipStream_t stream)
{
    const float* x     = (const float*)d_in[0];
    const float* wq    = (const float*)d_in[1];
    const float* bq    = (const float*)d_in[2];
    const float* wk    = (const float*)d_in[3];
    const float* bk    = (const float*)d_in[4];
    const float* wv    = (const float*)d_in[5];
    const float* bv    = (const float*)d_in[6];
    const float* wp    = (const float*)d_in[7];
    const float* bp    = (const float*)d_in[8];
    const float* wbias = (const float*)d_in[9];
    float* out = (float*)d_out;

    const size_t SZ_COPY = (size_t)B_ * T_ * DIM_;

    auto need = [](int SK) -> size_t {
        return 33554432u + (size_t)SK * 8388608u + 8388608u + 4194304u
             + 196608u + 65536u + 1024u;
    };
    int SK, write_both;
    char* R;
    if (ws_size >= need(4)) {
        SK = 4; write_both = 1; R = (char*)d_ws;
    } else {
        SK = 2; write_both = 0; R = (char*)(out + SZ_COPY);
    }
    size_t off = 0;
    unsigned short* Aexp  = (unsigned short*)(R + off); off += 33554432u;
    unsigned short* NDbuf = (unsigned short*)(R + off); off += (size_t)SK * 8388608u;
    unsigned short* SbT   = (unsigned short*)(R + off); off += 8388608u;
    unsigned short* Qbuf  = (unsigned short*)(R + off); off += 4194304u;
    unsigned short* Wcat  = (unsigned short*)(R + off); off += 196608u;
    unsigned short* wpb   = (unsigned short*)(R + off); off += 65536u;
    float*          bcat  = (float*)(R + off);

    ewb_kernel<<<2048, 256, 0, stream>>>(wbias, Aexp);
    wcat_kernel<<<192, 128, 0, stream>>>(wq, bq, wk, bk, wv, bv, Wcat, bcat);
    wpb_kernel<<<32, 256, 0, stream>>>(wp, wpb);
    xqkv_fused<<<dim3(T_ / 64, B_), 256, 0, stream>>>(x, Wcat, bcat, Qbuf, SbT);
    aft_gemm_8ph<<<dim3(4, 16, SK), 512, 0, stream>>>(Aexp, SbT, NDbuf, SK);
    if (SK == 4)
        epilogue_mfma<4><<<dim3(T_ / 64, B_), 256, 0, stream>>>(Qbuf, NDbuf, wpb, bp,
                                                                out, write_both);
    else
        epilogue_mfma<2><<<dim3(T_ / 64, B_), 256, 0, stream>>>(Qbuf, NDbuf, wpb, bp,
                                                                out, write_both);
    if (!write_both)
        dup_kernel<<<2048, 256, 0, stream>>>((const float4*)out,
                                             (float4*)(out + SZ_COPY),
                                             (int)(SZ_COPY / 4));
}

// Round 10
// 128.786 us; speedup vs baseline: 1.4349x; 1.0674x over previous
//
#include <hip/hip_runtime.h>
#include <hip/hip_bf16.h>

#define B_   8
#define DIM_ 512
#define T_   4096
#define H_   64
#define NC_  1024   // 2*B*H : cols 0..511 = eK*V (c=b*64+h), 512..1023 = eK

typedef __attribute__((ext_vector_type(8))) short short8;
typedef __attribute__((ext_vector_type(4))) float f32x4;

__device__ __forceinline__ unsigned short f2bf(float x) {
    __hip_bfloat16 h = __float2bfloat16(x);
    return *reinterpret_cast<unsigned short*>(&h);
}
__device__ __forceinline__ float bf2f(unsigned short u) {
    __hip_bfloat16 h = *reinterpret_cast<__hip_bfloat16*>(&u);
    return __bfloat162float(h);
}
__device__ __forceinline__ void gload16(const void* g, void* l) {
    __builtin_amdgcn_global_load_lds(
        (const __attribute__((address_space(1))) unsigned int*)g,
        (__attribute__((address_space(3))) unsigned int*)l, 16, 0, 0);
}

// ---------------------------------------------------------------------------
// K0: prep — blocks 0..191: Wcat row (+bcat); blocks 192..223: wpb chunk.
// 128 threads.
// ---------------------------------------------------------------------------
__global__ __launch_bounds__(128) void prep_kernel(
    const float* __restrict__ wq, const float* __restrict__ bq,
    const float* __restrict__ wk, const float* __restrict__ bk,
    const float* __restrict__ wv, const float* __restrict__ bv,
    const float* __restrict__ wp,
    unsigned short* __restrict__ Wcat, float* __restrict__ bcat,
    unsigned short* __restrict__ wpb)
{
    const int bid = blockIdx.x;
    const int tid = threadIdx.x;
    if (bid < 192) {
        const int r = bid;
        const float* src = (r < 64) ? (wq + (size_t)r * DIM_)
                         : (r < 128) ? (wk + (size_t)(r - 64) * DIM_)
                                     : (wv + (size_t)(r - 128) * DIM_);
        const int d4 = tid * 4;
        float4 v = *(const float4*)&src[d4];
        ushort4 o;
        o.x = f2bf(v.x); o.y = f2bf(v.y); o.z = f2bf(v.z); o.w = f2bf(v.w);
        *(ushort4*)&Wcat[(size_t)r * DIM_ + d4] = o;
        if (tid == 0)
            bcat[r] = (r < 64) ? bq[r] : (r < 128) ? bk[r - 64] : bv[r - 128];
    } else {
        // wpb: 512*64 = 32768 elems; 32 blocks x 128 thr x 8 elems
        const int i = (((bid - 192) * 128) + tid) * 8;
        float4 v0 = *(const float4*)&wp[i];
        float4 v1 = *(const float4*)&wp[i + 4];
        union { unsigned short s[8]; uint4 v; } o;
        o.s[0] = f2bf(v0.x); o.s[1] = f2bf(v0.y); o.s[2] = f2bf(v0.z); o.s[3] = f2bf(v0.w);
        o.s[4] = f2bf(v1.x); o.s[5] = f2bf(v1.y); o.s[6] = f2bf(v1.z); o.s[7] = f2bf(v1.w);
        *(uint4*)&wpb[i] = o.v;
    }
}

// ---------------------------------------------------------------------------
// K1: fused {xqkv (blocks 0..511)} || {ewb (blocks 512..2559)} — one launch.
// xqkv: stages x f32 tile to padded LDS, transposed col reads + f2bf -> MFMA;
//       writes Qb bf16 and SbT bf16.  x read exactly once.
// ewb:  Aexp[t][s] = bf16(exp(wbias[t][s])), grid-stride.
// Co-scheduling rationale: ewb is ~90% HBM-bound, xqkv ~35% — complementary.
// ---------------------------------------------------------------------------
__global__ __launch_bounds__(256) void ewb_xqkv(
    const float* __restrict__ x, const unsigned short* __restrict__ Wcat,
    const float* __restrict__ bcat, const float* __restrict__ wb,
    unsigned short* __restrict__ Qb, unsigned short* __restrict__ SbT,
    unsigned short* __restrict__ Aexp)
{
    __shared__ float xs[64 * 65];             // [d][t] f32, 16.6 KB
    __shared__ unsigned short Bs[192 * 64];   // [h][d] bf16, 24 KB

    const int tid = threadIdx.x;

    if (blockIdx.x >= 512) {
        // ---------------- ewb section ----------------
        const int n4 = T_ * T_ / 4;
        int idx = (blockIdx.x - 512) * 256 + tid;
        const int stride = (gridDim.x - 512) * 256;
        for (int i = idx; i < n4; i += stride) {
            float4 v = ((const float4*)wb)[i];
            ushort4 o;
            o.x = f2bf(__expf(v.x));
            o.y = f2bf(__expf(v.y));
            o.z = f2bf(__expf(v.z));
            o.w = f2bf(__expf(v.w));
            ((ushort4*)Aexp)[i] = o;
        }
        return;
    }

    // ---------------- xqkv section ----------------
    const int t0 = (blockIdx.x & 63) * 64;
    const int b  = blockIdx.x >> 6;
    const int wid = tid >> 6, lane = tid & 63;

    f32x4 acc[12];
    const f32x4 vzero = {0.f, 0.f, 0.f, 0.f};
#pragma unroll
    for (int f = 0; f < 12; f++) acc[f] = vzero;

    const int rs  = tid >> 3;
    const int ks8 = (tid & 7) * 8;
    const unsigned short* Bg = Wcat + (size_t)rs * DIM_ + ks8;

    const int xrow = tid >> 4;
    const int xt4  = (tid & 15) * 4;

    const int t_in = lane & 15;
    const int g    = lane >> 4;

    for (int d0 = 0; d0 < DIM_; d0 += 64) {
#pragma unroll
        for (int p = 0; p < 4; p++) {
            const int d = p * 16 + xrow;
            float4 v = *(const float4*)&x[((size_t)b * DIM_ + d0 + d) * T_ + t0 + xt4];
            *(float4*)&xs[d * 65 + xt4] = v;
        }
#pragma unroll
        for (int it = 0; it < 6; it++)
            gload16(Bg + (size_t)(it * 32) * DIM_ + d0, (void*)&Bs[(it * 256 + tid) * 8]);
        __syncthreads();

        const int row_a = wid * 16 + t_in;
#pragma unroll
        for (int kk = 0; kk < 2; kk++) {
            union { unsigned short s[8]; short8 v; } af;
#pragma unroll
            for (int j = 0; j < 8; j++)
                af.s[j] = f2bf(xs[(kk * 32 + g * 8 + j) * 65 + row_a]);
            const int kr = kk * 32 + g * 8;
#pragma unroll
            for (int fn = 0; fn < 12; fn++) {
                short8 bf = *(const short8*)&Bs[(fn * 16 + t_in) * 64 + kr];
                acc[fn] = __builtin_amdgcn_mfma_f32_16x16x32_bf16(af.v, bf, acc[fn], 0, 0, 0);
            }
        }
        __syncthreads();
    }

    const int cc = t_in;
    const int t_base = t0 + wid * 16 + g * 4;

#pragma unroll
    for (int fn = 0; fn < 4; fn++) {
        const int h = fn * 16 + cc;
        const float bb = bcat[h];
#pragma unroll
        for (int r = 0; r < 4; r++)
            Qb[((size_t)b * T_ + t_base + r) * H_ + h] = f2bf(acc[fn][r] + bb);
    }
#pragma unroll
    for (int f = 0; f < 4; f++) {
        const int h = f * 16 + cc;
        const float bK = bcat[64 + h];
        const float bV = bcat[128 + h];
        ushort4 pk, pe;
        float e0 = __expf(acc[4 + f][0] + bK), v0 = acc[8 + f][0] + bV;
        float e1 = __expf(acc[4 + f][1] + bK), v1 = acc[8 + f][1] + bV;
        float e2 = __expf(acc[4 + f][2] + bK), v2 = acc[8 + f][2] + bV;
        float e3 = __expf(acc[4 + f][3] + bK), v3 = acc[8 + f][3] + bV;
        pe.x = f2bf(e0); pe.y = f2bf(e1); pe.z = f2bf(e2); pe.w = f2bf(e3);
        pk.x = f2bf(e0 * v0); pk.y = f2bf(e1 * v1); pk.z = f2bf(e2 * v2); pk.w = f2bf(e3 * v3);
        *(ushort4*)&SbT[(size_t)(b * 64 + h) * T_ + t_base] = pk;
        *(ushort4*)&SbT[(size_t)(512 + b * 64 + h) * T_ + t_base] = pe;
    }
}

// ---------------------------------------------------------------------------
// K2: 8-phase 256x256 GEMM, BK=64, split-K=SK (runtime 2 or 4).
// (unchanged — absmax-clean, T2+T3+T4+T5 schedule)
// ---------------------------------------------------------------------------
__global__ __launch_bounds__(512, 2) void aft_gemm_8ph(
    const unsigned short* __restrict__ Aexp,
    const unsigned short* __restrict__ SbT,
    unsigned short* __restrict__ ND, int SK)
{
    __shared__ unsigned short smem[65536];   // 128 KB

    const int tid  = threadIdx.x;
    const int wid  = tid >> 6, lane = tid & 63;
    const int wm   = wid >> 2, wn = wid & 3;
    const int la   = lane & 15, lg = lane >> 4;

    const int nwg = 64 * SK;
    const int lin = blockIdx.x + blockIdx.y * 4 + blockIdx.z * 64;
    const int cpx = nwg >> 3;
    const int wg  = (lin & 7) * cpx + (lin >> 3);
    const int c0  = (wg & 3) * 256;
    const int t0  = ((wg >> 2) & 15) * 256;
    const int ks  = wg >> 6;
    const int Kblk  = T_ / SK;
    const int sbase = ks * Kblk;
    const int NT    = Kblk >> 6;

    f32x4 acc[8][4];
    const f32x4 vzero = {0.f, 0.f, 0.f, 0.f};
#pragma unroll
    for (int i = 0; i < 8; i++)
#pragma unroll
        for (int j = 0; j < 4; j++) acc[i][j] = vzero;

    const int lr8 = tid >> 3, c16 = tid & 7;

    auto stA = [&](int q, int T, int p) {
        const int tr = (lr8 < 32) ? (32 * q + lr8) : (96 + 32 * q + lr8);
        const unsigned short* src = Aexp + (size_t)(t0 + tr) * T_
                                  + sbase + T * 64 + ((c16 ^ (tr & 7)) * 8);
        gload16(src, (void*)&smem[p * 32768 + tr * 64 + c16 * 8]);
    };
    auto stB = [&](int h, int j, int T, int p) {
        const int tr = 128 * h + 64 * j + lr8;
        const unsigned short* src = SbT + (size_t)(c0 + tr) * T_
                                  + sbase + T * 64 + ((c16 ^ (tr & 7)) * 8);
        gload16(src, (void*)&smem[p * 32768 + 16384 + tr * 64 + c16 * 8]);
    };

    stB(0, 0, 0, 0); stB(0, 1, 0, 0); stB(1, 0, 0, 0); stB(1, 1, 0, 0);
    stA(0, 0, 0);    stA(1, 0, 0);    stA(2, 0, 0);    stA(3, 0, 0);
    stB(0, 0, 1, 1); stB(0, 1, 1, 1); stB(1, 0, 1, 1); stB(1, 1, 1, 1);
    stA(0, 1, 1);    stA(1, 1, 1);
    asm volatile("s_waitcnt vmcnt(6)" ::: "memory");
    __builtin_amdgcn_s_barrier();

    for (int kt = 0; kt < NT; ++kt) {
        const int p = kt & 1;
        const unsigned short* Ab = smem + p * 32768;
        const unsigned short* Bb = Ab + 16384;
        short8 bfr[4][2];

        {
            short8 af[2][2];
#pragma unroll
            for (int i = 0; i < 2; ++i) {
                const int row = 128 * wm + 16 * i + la;
#pragma unroll
                for (int kk = 0; kk < 2; ++kk)
                    af[i][kk] = *(const short8*)&Ab[row * 64 + (((kk * 4 + lg) ^ (row & 7)) * 8)];
            }
#pragma unroll
            for (int fn = 0; fn < 4; ++fn) {
                const int row = 64 * wn + 16 * fn + la;
#pragma unroll
                for (int kk = 0; kk < 2; ++kk)
                    bfr[fn][kk] = *(const short8*)&Bb[row * 64 + (((kk * 4 + lg) ^ (row & 7)) * 8)];
            }
            if (kt + 1 < NT) { stA(2, kt + 1, 1 - p); stA(3, kt + 1, 1 - p); }
            __builtin_amdgcn_s_barrier();
            asm volatile("s_waitcnt lgkmcnt(0)" ::: "memory");
            __builtin_amdgcn_sched_barrier(0);
            __builtin_amdgcn_s_setprio(1);
#pragma unroll
            for (int i = 0; i < 2; ++i)
#pragma unroll
                for (int fn = 0; fn < 4; ++fn)
#pragma unroll
                    for (int kk = 0; kk < 2; ++kk)
                        acc[i][fn] = __builtin_amdgcn_mfma_f32_16x16x32_bf16(
                            af[i][kk], bfr[fn][kk], acc[i][fn], 0, 0, 0);
            __builtin_amdgcn_s_setprio(0);
            __builtin_amdgcn_s_barrier();
        }
#pragma unroll
        for (int q = 1; q < 4; ++q) {
            short8 af[2][2];
#pragma unroll
            for (int i = 0; i < 2; ++i) {
                const int row = 128 * wm + 16 * (2 * q + i) + la;
#pragma unroll
                for (int kk = 0; kk < 2; ++kk)
                    af[i][kk] = *(const short8*)&Ab[row * 64 + (((kk * 4 + lg) ^ (row & 7)) * 8)];
            }
            if (kt + 2 < NT) {
                if (q == 1)      { stB(0, 0, kt + 2, p); stB(0, 1, kt + 2, p); }
                else if (q == 2) { stB(1, 0, kt + 2, p); stB(1, 1, kt + 2, p); }
                else             { stA(0, kt + 2, p);    stA(1, kt + 2, p);    }
            }
            if (q == 3) asm volatile("s_waitcnt vmcnt(6)" ::: "memory");
            __builtin_amdgcn_s_barrier();
            asm volatile("s_waitcnt lgkmcnt(0)" ::: "memory");
            __builtin_amdgcn_sched_barrier(0);
            __builtin_amdgcn_s_setprio(1);
#pragma unroll
            for (int i = 0; i < 2; ++i)
#pragma unroll
                for (int fn = 0; fn < 4; ++fn)
#pragma unroll
                    for (int kk = 0; kk < 2; ++kk)
                        acc[2 * q + i][fn] = __builtin_amdgcn_mfma_f32_16x16x32_bf16(
                            af[i][kk], bfr[fn][kk], acc[2 * q + i][fn], 0, 0, 0);
            __builtin_amdgcn_s_setprio(0);
            __builtin_amdgcn_s_barrier();
        }
    }

    unsigned short* NDp = ND + (size_t)ks * T_ * NC_;
    const int r4 = lg * 4;
#pragma unroll
    for (int fm = 0; fm < 8; ++fm)
#pragma unroll
        for (int fn = 0; fn < 4; ++fn)
#pragma unroll
            for (int r = 0; r < 4; ++r) {
                const int t = t0 + 128 * wm + 16 * fm + r4 + r;
                const int c = c0 + 64 * wn + 16 * fn + la;
                NDp[(size_t)t * NC_ + c] = f2bf(acc[fm][fn][r]);
            }
}

// ---------------------------------------------------------------------------
// K3: epilogue via MFMA.  grid (T/64, B), block 256 (4 waves).
// SK compile-time; pp-outer unrolled short8 loads (round-8 lesson).
// ---------------------------------------------------------------------------
template <int SK>
__global__ __launch_bounds__(256) void epilogue_mfma(
    const unsigned short* __restrict__ Qb, const unsigned short* __restrict__ ND,
    const unsigned short* __restrict__ wpb, const float* __restrict__ bp,
    float* __restrict__ out, int write_both)
{
    __shared__ unsigned short smem[36864];      // 72 KB
    unsigned short* y_s  = smem;                // 8 KB, swizzled [t][h]
    unsigned short* wp_s = smem + 4096;         // 64 KB, swizzled [d][h]
    float* st = (float*)smem;                   // bounce [64][260] f32

    const int tid  = threadIdx.x;
    const int t0   = blockIdx.x * 64;
    const int b    = blockIdx.y;
    const int wid  = tid >> 6, lane = tid & 63;
    const size_t SZ_COPY = (size_t)B_ * T_ * DIM_;

    {
        const int rs = tid >> 3;
        const int c8 = tid & 7;
#pragma unroll
        for (int p = 0; p < 16; p++) {
            const int row = p * 32 + rs;
            gload16(wpb + (size_t)row * 64 + ((c8 ^ (row & 7)) << 3),
                    (void*)&wp_s[((size_t)row * 8 + c8) * 8]);
        }
    }
    {
        const int t   = tid >> 2;
        const int h16 = (tid & 3) * 16;
        const size_t qoff = ((size_t)b * T_ + t0 + t) * H_ + h16;
        const size_t noff = (size_t)(t0 + t) * NC_ + b * 64 + h16;

        float num[16], den[16];
#pragma unroll
        for (int e = 0; e < 16; e++) { num[e] = 0.f; den[e] = 0.f; }
#pragma unroll
        for (int pp = 0; pp < SK; ++pp) {
            const unsigned short* P = ND + (size_t)pp * T_ * NC_ + noff;
            short8 n0 = *(const short8*)&P[0];
            short8 n1 = *(const short8*)&P[8];
            short8 d0 = *(const short8*)&P[512];
            short8 d1 = *(const short8*)&P[520];
#pragma unroll
            for (int e = 0; e < 8; e++) {
                num[e]     += bf2f((unsigned short)n0[e]);
                num[8 + e] += bf2f((unsigned short)n1[e]);
                den[e]     += bf2f((unsigned short)d0[e]);
                den[8 + e] += bf2f((unsigned short)d1[e]);
            }
        }
        short8 q0 = *(const short8*)&Qb[qoff];
        short8 q1 = *(const short8*)&Qb[qoff + 8];
        float yv[16];
#pragma unroll
        for (int e = 0; e < 8; e++) {
            float qa = bf2f((unsigned short)q0[e]);
            float qb = bf2f((unsigned short)q1[e]);
            yv[e]     = (1.f / (1.f + __expf(-qa))) * num[e] / den[e];
            yv[8 + e] = (1.f / (1.f + __expf(-qb))) * num[8 + e] / den[8 + e];
        }
#pragma unroll
        for (int u = 0; u < 2; u++) {
            const int h8 = (tid & 3) * 2 + u;
            union { unsigned short s[8]; short8 v; } pk;
#pragma unroll
            for (int e = 0; e < 8; e++) pk.s[e] = f2bf(yv[u * 8 + e]);
            *(short8*)((char*)y_s + t * 128 + ((h8 ^ (t & 7)) << 4)) = pk.v;
        }
    }
    __syncthreads();

    f32x4 acc[32];
    const f32x4 vzero = {0.f, 0.f, 0.f, 0.f};
#pragma unroll
    for (int f = 0; f < 32; f++) acc[f] = vzero;

    const int ra = wid * 16 + (lane & 15);
    short8 af[2];
#pragma unroll
    for (int kk = 0; kk < 2; kk++)
        af[kk] = *(const short8*)((char*)y_s + ra * 128 +
                                  (((kk * 4 + (lane >> 4)) ^ (ra & 7)) << 4));
#pragma unroll
    for (int fn = 0; fn < 32; fn++) {
        const int rb = fn * 16 + (lane & 15);
#pragma unroll
        for (int kk = 0; kk < 2; kk++) {
            short8 bf = *(const short8*)((char*)wp_s + rb * 128 +
                                         (((kk * 4 + (lane >> 4)) ^ (rb & 7)) << 4));
            acc[fn] = __builtin_amdgcn_mfma_f32_16x16x32_bf16(af[kk], bf, acc[fn], 0, 0, 0);
        }
    }
    __syncthreads();

    const int g  = lane >> 4;
    const int cc = lane & 15;
    float4 bb01[2];
    bb01[0] = *(const float4*)&bp[lane * 4];
    bb01[1] = *(const float4*)&bp[256 + lane * 4];

#pragma unroll
    for (int ch = 0; ch < 2; ch++) {
        if (ch) __syncthreads();
#pragma unroll
        for (int f = 0; f < 16; f++)
#pragma unroll
            for (int r = 0; r < 4; r++)
                st[(wid * 16 + g * 4 + r) * 260 + f * 16 + cc] = acc[ch * 16 + f][r];
        __syncthreads();
        const float4 bb = bb01[ch];
#pragma unroll
        for (int it = 0; it < 16; it++) {
            const int row = it * 4 + wid;
            float4 v = *(const float4*)&st[row * 260 + lane * 4];
            float4 o = {v.x + bb.x, v.y + bb.y, v.z + bb.z, v.w + bb.w};
            const size_t obase = ((size_t)b * T_ + t0 + row) * DIM_ + ch * 256 + lane * 4;
            *(float4*)&out[obase] = o;
            if (write_both)
                *(float4*)&out[SZ_COPY + obase] = o;
        }
    }
}

__global__ void dup_kernel(const float4* __restrict__ src, float4* __restrict__ dst, int n4)
{
    int idx = blockIdx.x * blockDim.x + threadIdx.x;
    int stride = gridDim.x * blockDim.x;
    for (int k = idx; k < n4; k += stride) dst[k] = src[k];
}

extern "C" void kernel_launch(void* const* d_in, const int* in_sizes, int n_in,
                              void* d_out, int out_size, void* d_ws, size_t ws_size,
                              hipStream_t stream)
{
    const float* x     = (const float*)d_in[0];
    const float* wq    = (const float*)d_in[1];
    const float* bq    = (const float*)d_in[2];
    const float* wk    = (const float*)d_in[3];
    const float* bk    = (const float*)d_in[4];
    const float* wv    = (const float*)d_in[5];
    const float* bv    = (const float*)d_in[6];
    const float* wp    = (const float*)d_in[7];
    const float* bp    = (const float*)d_in[8];
    const float* wbias = (const float*)d_in[9];
    float* out = (float*)d_out;

    const size_t SZ_COPY = (size_t)B_ * T_ * DIM_;

    auto need = [](int SK) -> size_t {
        return 33554432u + (size_t)SK * 8388608u + 8388608u + 4194304u
             + 196608u + 65536u + 1024u;
    };
    int SK, write_both;
    char* R;
    if (ws_size >= need(4)) {
        SK = 4; write_both = 1; R = (char*)d_ws;
    } else {
        SK = 2; write_both = 0; R = (char*)(out + SZ_COPY);
    }
    size_t off = 0;
    unsigned short* Aexp  = (unsigned short*)(R + off); off += 33554432u;
    unsigned short* NDbuf = (unsigned short*)(R + off); off += (size_t)SK * 8388608u;
    unsigned short* SbT   = (unsigned short*)(R + off); off += 8388608u;
    unsigned short* Qbuf  = (unsigned short*)(R + off); off += 4194304u;
    unsigned short* Wcat  = (unsigned short*)(R + off); off += 196608u;
    unsigned short* wpb   = (unsigned short*)(R + off); off += 65536u;
    float*          bcat  = (float*)(R + off);

    prep_kernel<<<224, 128, 0, stream>>>(wq, bq, wk, bk, wv, bv, wp, Wcat, bcat, wpb);
    ewb_xqkv<<<2560, 256, 0, stream>>>(x, Wcat, bcat, wbias, Qbuf, SbT, Aexp);
    aft_gemm_8ph<<<dim3(4, 16, SK), 512, 0, stream>>>(Aexp, SbT, NDbuf, SK);
    if (SK == 4)
        epilogue_mfma<4><<<dim3(T_ / 64, B_), 256, 0, stream>>>(Qbuf, NDbuf, wpb, bp,
                                                                out, write_both);
    else
        epilogue_mfma<2><<<dim3(T_ / 64, B_), 256, 0, stream>>>(Qbuf, NDbuf, wpb, bp,
                                                                out, write_both);
    if (!write_both)
        dup_kernel<<<2048, 256, 0, stream>>>((const float4*)out,
                                             (float4*)(out + SZ_COPY),
                                             (int)(SZ_COPY / 4));
}